// Round 3
// baseline (75.700 us; speedup 1.0000x reference)
//
#include <hip/hip_runtime.h>
#include <math.h>

#define N_PIX 2304   // 48*48
#define CDIM  256
#define KDIM  2048
#define TOPK  204

typedef __attribute__((ext_vector_type(8))) short bf16x8;
typedef __attribute__((ext_vector_type(4))) float f32x4;

__device__ __forceinline__ unsigned short f2bf(float f) {
    unsigned u = __float_as_uint(f);
    unsigned r = u + 0x7FFFu + ((u >> 16) & 1u);
    return (unsigned short)(r >> 16);
}

__device__ __forceinline__ void gload16(const void* g, void* l) {
    __builtin_amdgcn_global_load_lds((const __attribute__((address_space(1))) void*)g,
                                     (__attribute__((address_space(3))) void*)l,
                                     16, 0, 0);
}

// ================= Kernel 1: all prep (x-norm/xn/copy + feat-norm/fnorm/F2T) =================
__global__ __launch_bounds__(256) void k_prep(const float* __restrict__ x,
                                              const float* __restrict__ feat,
                                              const float* __restrict__ label,
                                              float* __restrict__ out,
                                              unsigned short* __restrict__ xn,
                                              unsigned short* __restrict__ fnorm,
                                              unsigned short* __restrict__ F2T) {
    __shared__ __align__(16) char sm[68608];
    int b = blockIdx.x, t = threadIdx.x;

    if (b < 36) {
        // ---- x branch: 64 pixels per block ----
        float* tile  = (float*)sm;              // [256][65]
        float* part  = (float*)(sm + 66560);    // [4][64]
        float* rnloc = (float*)(sm + 67584);    // [64]
        int p0 = b * 64;
        #pragma unroll
        for (int i = 0; i < 64; ++i) {
            int idx = t + i * 256;
            int c = idx >> 6, pl = idx & 63;
            float v = x[c * N_PIX + p0 + pl];
            tile[c * 65 + pl] = v;
            out[c * N_PIX + p0 + pl] = v;       // passthrough copy
        }
        __syncthreads();
        {
            int pixel = t & 63, q = t >> 6;
            float s = 0.f;
            #pragma unroll
            for (int i = 0; i < 64; ++i) {
                float v = tile[(q * 64 + i) * 65 + pixel];
                s = fmaf(v, v, s);
            }
            part[q * 64 + pixel] = s;
        }
        __syncthreads();
        if (t < 64) {
            float tt = part[t] + part[64 + t] + part[128 + t] + part[192 + t];
            rnloc[t] = 1.0f / fmaxf(sqrtf(tt), 1e-12f);
        }
        __syncthreads();
        {
            int p = t >> 2, cq = t & 3;
            float rn = rnloc[p];
            #pragma unroll
            for (int j = 0; j < 8; ++j) {
                bf16x8 pk;
                #pragma unroll
                for (int jj = 0; jj < 8; ++jj)
                    pk[jj] = (short)f2bf(tile[(cq * 64 + j * 8 + jj) * 65 + p] * rn);
                *(bf16x8*)(xn + (size_t)(p0 + p) * CDIM + cq * 64 + j * 8) = pk;
            }
        }
    } else {
        // ---- feat branch: 64 rows per block ----
        float* tile = (float*)sm;               // [64][257]
        float* rnl  = (float*)(sm + 65792);     // [64]
        int r0 = (b - 36) * 64;
        #pragma unroll
        for (int i = 0; i < 64; ++i) {
            int idx = t + i * 256;
            int r = idx >> 8, c = idx & 255;
            tile[r * 257 + c] = feat[(size_t)(r0 + r) * CDIM + c];
        }
        __syncthreads();
        int row = t >> 2, q = t & 3;
        float s = 0.f;
        #pragma unroll
        for (int i = 0; i < 64; ++i) {
            float v = tile[row * 257 + q * 64 + i];
            s = fmaf(v, v, s);
        }
        s += __shfl_xor(s, 1, 64);
        s += __shfl_xor(s, 2, 64);
        float rn = 1.0f / fmaxf(sqrtf(s), 1e-12f);
        if (q == 0) rnl[row] = rn;
        // fnorm row-major bf16
        #pragma unroll
        for (int j = 0; j < 8; ++j) {
            bf16x8 pk;
            #pragma unroll
            for (int jj = 0; jj < 8; ++jj)
                pk[jj] = (short)f2bf(tile[row * 257 + q * 64 + j * 8 + jj] * rn);
            *(bf16x8*)(fnorm + (size_t)(r0 + row) * CDIM + q * 64 + j * 8) = pk;
        }
        __syncthreads();
        // F2T transposed chunk: F2T[c][r0+r], packed ushort2 over r
        {
            int rp = (t & 31) * 2, cg = t >> 5;
            float rn0 = rnl[rp], rn1 = rnl[rp + 1];
            #pragma unroll
            for (int i = 0; i < 32; ++i) {
                int c = i * 8 + cg;
                unsigned u0 = f2bf(tile[rp * 257 + c] * rn0);
                unsigned u1 = f2bf(tile[(rp + 1) * 257 + c] * rn1);
                *(unsigned*)(F2T + (size_t)c * KDIM + r0 + rp) = u0 | (u1 << 16);
            }
        }
        // label rows 256..259
        {
            int ch = t >> 6, r = t & 63;
            F2T[(size_t)(256 + ch) * KDIM + r0 + r] = f2bf(label[(size_t)(r0 + r) * 4 + ch]);
        }
        // zero rows 260..319
        #pragma unroll
        for (int i = 0; i < 15; ++i) {
            int idx = t + i * 256;
            int zr = idx >> 6, zc = idx & 63;
            F2T[(size_t)(260 + zr) * KDIM + r0 + zc] = 0;
        }
    }
}

// ================= Kernel 2: fused score GEMM + softmax + top-204 + W write =================
// block = 16 pixel rows x full 2048 kdim. 4 waves split N (512 each).
__global__ __launch_bounds__(256, 1) void k_scorew(const unsigned short* __restrict__ xn,
                                                   const unsigned short* __restrict__ fn,
                                                   float* __restrict__ score,
                                                   unsigned short* __restrict__ Wm) {
    __shared__ __align__(16) char sm[131344];
    int t = threadIdx.x, l = t & 63, w = t >> 6;
    int p0 = blockIdx.x * 16;

    unsigned short* Bst = (unsigned short*)sm;   // [2][128*256] bf16 = 2*65536 B

    // A fragments (16 pixel rows, all K=256) -> registers
    bf16x8 av[8];
    #pragma unroll
    for (int ks = 0; ks < 8; ++ks)
        av[ks] = *(const bf16x8*)(xn + (size_t)(p0 + (l & 15)) * CDIM + ks * 32 + (l >> 4) * 8);

    f32x4 acc[32] = {};

    // stage one 128-row x 256-k panel of fnorm into Bst[buf] (chunk-XOR swizzled source)
#define STAGE(np, buf)                                                              \
    {                                                                               \
        const unsigned short* src = fn + (size_t)(np) * 128 * CDIM;                 \
        unsigned short* dst = Bst + (buf) * 32768 + (0 * 256 + w * 64) * 8;         \
        _Pragma("unroll")                                                           \
        for (int i = 0; i < 16; ++i) {                                              \
            int idx = i * 256 + t;                                                  \
            int row = idx >> 5, ch = idx & 31;                                      \
            int sch = ch ^ (row & 7);                                               \
            gload16(src + (size_t)row * CDIM + sch * 8,                             \
                    Bst + (buf) * 32768 + (i * 256 + w * 64) * 8);                  \
        }                                                                           \
        (void)dst;                                                                  \
    }

    STAGE(0, 0);
    __syncthreads();   // implies vmcnt(0)

    #pragma unroll
    for (int np = 0; np < 16; ++np) {
        int buf = np & 1;
        if (np < 15) STAGE(np + 1, buf ^ 1);
        const unsigned short* B = Bst + buf * 32768;
        #pragma unroll
        for (int ks = 0; ks < 8; ++ks) {
            #pragma unroll
            for (int f = 0; f < 2; ++f) {
                int row = w * 32 + f * 16 + (l & 15);
                int ch  = (ks * 4 + (l >> 4)) ^ (row & 7);
                bf16x8 bv = *(const bf16x8*)(B + (size_t)row * CDIM + ch * 8);
                acc[np * 2 + f] = __builtin_amdgcn_mfma_f32_16x16x32_bf16(av[ks], bv, acc[np * 2 + f], 0, 0, 0);
            }
        }
        asm volatile("s_waitcnt vmcnt(0)" ::: "memory");
        __syncthreads();
    }

    // ---- transpose through LDS (swizzled), coalesced score write ----
    float* slds = (float*)sm;    // [16][2052] f32, 16B-chunk swizzle c^((c>>5)&7)
    #pragma unroll
    for (int fr = 0; fr < 32; ++fr) {
        int colbase = (fr >> 1) * 128 + w * 32 + (fr & 1) * 16 + (l & 15);
        int c16  = colbase >> 2;
        int sc16 = c16 ^ ((c16 >> 5) & 7);
        #pragma unroll
        for (int r = 0; r < 4; ++r) {
            int row = (l >> 4) * 4 + r;
            slds[row * 2052 + sc16 * 4 + (colbase & 3)] = acc[fr][r];
        }
    }
    __syncthreads();

    {
        int row = t >> 4;
        #pragma unroll
        for (int j = 0; j < 32; ++j) {
            int c16  = j * 16 + (t & 15);
            int sc16 = c16 ^ ((c16 >> 5) & 7);
            float4 v = *(const float4*)&slds[row * 2052 + sc16 * 4];
            *(float4*)&score[(size_t)(p0 + row) * KDIM + c16 * 4] = v;
        }
    }

    // ---- reload rows wave-local: wave w owns rows w*4 .. w*4+3, lane l owns cols l*32..+31 ----
    float sv[4][32];
    #pragma unroll
    for (int rr = 0; rr < 4; ++rr) {
        int row = w * 4 + rr;
        #pragma unroll
        for (int jj = 0; jj < 8; ++jj) {
            int c16  = l * 8 + jj;
            int sc16 = c16 ^ ((c16 >> 5) & 7);
            *(float4*)&sv[rr][jj * 4] = *(const float4*)&slds[row * 2052 + sc16 * 4];
        }
    }

    // exp in place + denom (wave-local full reduce)
    float rd[4];
    #pragma unroll
    for (int rr = 0; rr < 4; ++rr) {
        float d = 0.f;
        #pragma unroll
        for (int i = 0; i < 32; ++i) { sv[rr][i] = __expf(sv[rr][i]); d += sv[rr][i]; }
        #pragma unroll
        for (int off = 32; off; off >>= 1) d += __shfl_xor(d, off, 64);
        rd[rr] = 1.0f / d;
    }

    // 20-iter bisection in exp domain, 4 rows in lockstep, zero barriers
    float lo[4] = {0.2f, 0.2f, 0.2f, 0.2f};
    float hi[4] = {3.0f, 3.0f, 3.0f, 3.0f};
    for (int it = 0; it < 20; ++it) {
        float mid0 = 0.5f * (lo[0] + hi[0]), mid1 = 0.5f * (lo[1] + hi[1]);
        float mid2 = 0.5f * (lo[2] + hi[2]), mid3 = 0.5f * (lo[3] + hi[3]);
        int c01 = 0, c23 = 0;
        #pragma unroll
        for (int i = 0; i < 32; ++i) {
            c01 += (sv[0][i] > mid0) ? 1 : 0;
            c01 += (sv[1][i] > mid1) ? (1 << 16) : 0;
            c23 += (sv[2][i] > mid2) ? 1 : 0;
            c23 += (sv[3][i] > mid3) ? (1 << 16) : 0;
        }
        #pragma unroll
        for (int off = 32; off; off >>= 1) {
            c01 += __shfl_xor(c01, off, 64);
            c23 += __shfl_xor(c23, off, 64);
        }
        int cnt[4] = {c01 & 0xFFFF, c01 >> 16, c23 & 0xFFFF, c23 >> 16};
        #pragma unroll
        for (int rr = 0; rr < 4; ++rr) {
            float mid = 0.5f * (lo[rr] + hi[rr]);
            if (cnt[rr] >= TOPK) lo[rr] = mid; else hi[rr] = mid;
        }
    }

    // masked softmax weights, bf16, coalesced write
    #pragma unroll
    for (int rr = 0; rr < 4; ++rr) {
        int row = w * 4 + rr;
        #pragma unroll
        for (int j = 0; j < 4; ++j) {
            bf16x8 pk;
            #pragma unroll
            for (int jj = 0; jj < 8; ++jj) {
                float v = sv[rr][j * 8 + jj];
                pk[jj] = (short)((v > lo[rr]) ? f2bf(v * rd[rr]) : (unsigned short)0);
            }
            *(bf16x8*)(Wm + (size_t)(p0 + row) * KDIM + l * 32 + j * 8) = pk;
        }
    }
}

// ================= Kernel 3: GEMM2  out_xy^T = W(2304x2048) @ F2T(320x2048)^T =================
__global__ __launch_bounds__(256) void k_gemm2(const unsigned short* __restrict__ W,
                                               const unsigned short* __restrict__ F2T,
                                               float* __restrict__ out) {
    __shared__ __align__(16) char sm[65536];
    int t = threadIdx.x, l = t & 63, w = t >> 6;
    int m0 = blockIdx.y * 64, n0 = blockIdx.x * 64;
    char* wbase = sm + w * 16384;
    int   kb    = w * 512;

    f32x4 acc[4][4] = {};

    #pragma unroll
    for (int i = 0; i < 4; ++i) {
        int row = i * 16 + (l >> 2);
        int ch  = (l & 3) ^ ((row >> 1) & 3);
        gload16(W   + (size_t)(m0 + row) * KDIM + kb + ch * 8, wbase + i * 1024);
        gload16(F2T + (size_t)(n0 + row) * KDIM + kb + ch * 8, wbase + 8192 + i * 1024);
    }

    for (int ks = 0; ks < 16; ++ks) {
        int cur = ks & 1;
        if (ks < 15) {
            int koff = kb + (ks + 1) * 32;
            #pragma unroll
            for (int i = 0; i < 4; ++i) {
                int row = i * 16 + (l >> 2);
                int ch  = (l & 3) ^ ((row >> 1) & 3);
                gload16(W   + (size_t)(m0 + row) * KDIM + koff + ch * 8, wbase + (cur ^ 1) * 4096 + i * 1024);
                gload16(F2T + (size_t)(n0 + row) * KDIM + koff + ch * 8, wbase + 8192 + (cur ^ 1) * 4096 + i * 1024);
            }
            asm volatile("s_waitcnt vmcnt(8)" ::: "memory");
        } else {
            asm volatile("s_waitcnt vmcnt(0)" ::: "memory");
        }
        bf16x8 av[4], bv[4];
        #pragma unroll
        for (int mi = 0; mi < 4; ++mi) {
            int R = mi * 16 + (l & 15);
            av[mi] = *(const bf16x8*)(wbase + cur * 4096 + R * 64 + (((l >> 4) ^ ((R >> 1) & 3)) << 4));
        }
        #pragma unroll
        for (int ni = 0; ni < 4; ++ni) {
            int R = ni * 16 + (l & 15);
            bv[ni] = *(const bf16x8*)(wbase + 8192 + cur * 4096 + R * 64 + (((l >> 4) ^ ((R >> 1) & 3)) << 4));
        }
        #pragma unroll
        for (int mi = 0; mi < 4; ++mi)
            #pragma unroll
            for (int ni = 0; ni < 4; ++ni)
                acc[mi][ni] = __builtin_amdgcn_mfma_f32_16x16x32_bf16(av[mi], bv[ni], acc[mi][ni], 0, 0, 0);
    }

    __syncthreads();
    float* tl = (float*)sm;                 // [2][64][65] f32
    if (w >= 2) {
        float* dst = tl + (w - 2) * 64 * 65;
        #pragma unroll
        for (int mi = 0; mi < 4; ++mi)
            #pragma unroll
            for (int ni = 0; ni < 4; ++ni) {
                int rr = mi * 16 + (l >> 4) * 4;
                int cc = ni * 16 + (l & 15);
                #pragma unroll
                for (int r = 0; r < 4; ++r)
                    dst[(rr + r) * 65 + cc] = acc[mi][ni][r];
            }
    }
    __syncthreads();
    if (w < 2) {
        float* dst = tl + w * 64 * 65;
        #pragma unroll
        for (int mi = 0; mi < 4; ++mi)
            #pragma unroll
            for (int ni = 0; ni < 4; ++ni) {
                int rr = mi * 16 + (l >> 4) * 4;
                int cc = ni * 16 + (l & 15);
                #pragma unroll
                for (int r = 0; r < 4; ++r)
                    dst[(rr + r) * 65 + cc] += acc[mi][ni][r];
            }
    }
    __syncthreads();
    int pl = t & 63, cg = t >> 6;
    #pragma unroll
    for (int i = 0; i < 16; ++i) {
        int cc = cg * 16 + i;
        int c_out = n0 + cc;
        int orow;
        if (c_out < 256) orow = 256 + c_out;
        else if (c_out < 260) orow = 512 + (c_out - 256);
        else continue;
        out[(size_t)orow * N_PIX + m0 + pl] = tl[pl * 65 + cc] + tl[64 * 65 + pl * 65 + cc];
    }
}

extern "C" void kernel_launch(void* const* d_in, const int* in_sizes, int n_in,
                              void* d_out, int out_size, void* d_ws, size_t ws_size,
                              hipStream_t stream) {
    const float* x     = (const float*)d_in[0];   // (1,256,48,48)
    const float* feat  = (const float*)d_in[1];   // (2048,256)
    const float* label = (const float*)d_in[2];   // (2048,4)
    float* out   = (float*)d_out;                 // (1,516,48,48) then score
    float* score = out + 516 * N_PIX;             // (2304,2048)

    char* ws = (char*)d_ws;
    unsigned short* xn    = (unsigned short*)(ws);             // 2304*256*2 = 1179648
    unsigned short* fnorm = (unsigned short*)(ws + 1179648);   // 2048*256*2 = 1048576
    unsigned short* F2T   = (unsigned short*)(ws + 2228224);   // 320*2048*2 = 1310720
    unsigned short* Wm    = (unsigned short*)(ws + 3538944);   // 2304*2048*2 = 9437184

    k_prep  <<<68,           256, 0, stream>>>(x, feat, label, out, xn, fnorm, F2T);
    k_scorew<<<144,          256, 0, stream>>>(xn, fnorm, score, Wm);
    k_gemm2 <<<dim3(5, 36),  256, 0, stream>>>(Wm, F2T, out);
}

// Round 4
// 57.469 us; speedup vs baseline: 1.3172x; 1.3172x over previous
//
#include <hip/hip_runtime.h>
#include <math.h>

#define N_PIX 2304   // 48*48
#define CDIM  256
#define KDIM  2048
#define TOPK  204

typedef __attribute__((ext_vector_type(8))) short bf16x8;
typedef __attribute__((ext_vector_type(4))) float f32x4;

__device__ __forceinline__ unsigned short f2bf(float f) {
    unsigned u = __float_as_uint(f);
    unsigned r = u + 0x7FFFu + ((u >> 16) & 1u);
    return (unsigned short)(r >> 16);
}

__device__ __forceinline__ void gload16(const void* g, void* l) {
    __builtin_amdgcn_global_load_lds((const __attribute__((address_space(1))) void*)g,
                                     (__attribute__((address_space(3))) void*)l,
                                     16, 0, 0);
}

// ================= Kernel 1: all prep (x-norm/xn/copy + feat-norm/fnorm/F2T[raw]) =================
__global__ __launch_bounds__(256) void k_prep(const float* __restrict__ x,
                                              const float* __restrict__ feat,
                                              const float* __restrict__ label,
                                              float* __restrict__ out,
                                              unsigned short* __restrict__ xn,
                                              unsigned short* __restrict__ fnorm,
                                              unsigned short* __restrict__ F2T) {
    __shared__ __align__(16) char sm[68608];
    int b = blockIdx.x, t = threadIdx.x;

    if (b < 36) {
        // ---- x branch: 64 pixels per block ----
        float* tile  = (float*)sm;              // [256][65]
        float* part  = (float*)(sm + 66560);    // [4][64]
        float* rnloc = (float*)(sm + 67584);    // [64]
        int p0 = b * 64;
        #pragma unroll
        for (int i = 0; i < 64; ++i) {
            int idx = t + i * 256;
            int c = idx >> 6, pl = idx & 63;
            float v = x[c * N_PIX + p0 + pl];
            tile[c * 65 + pl] = v;
            out[c * N_PIX + p0 + pl] = v;       // passthrough copy
        }
        __syncthreads();
        {
            int pixel = t & 63, q = t >> 6;
            float s = 0.f;
            #pragma unroll
            for (int i = 0; i < 64; ++i) {
                float v = tile[(q * 64 + i) * 65 + pixel];
                s = fmaf(v, v, s);
            }
            part[q * 64 + pixel] = s;
        }
        __syncthreads();
        if (t < 64) {
            float tt = part[t] + part[64 + t] + part[128 + t] + part[192 + t];
            rnloc[t] = 1.0f / fmaxf(sqrtf(tt), 1e-12f);
        }
        __syncthreads();
        {
            int p = t >> 2, cq = t & 3;
            float rn = rnloc[p];
            #pragma unroll
            for (int j = 0; j < 8; ++j) {
                bf16x8 pk;
                #pragma unroll
                for (int jj = 0; jj < 8; ++jj)
                    pk[jj] = (short)f2bf(tile[(cq * 64 + j * 8 + jj) * 65 + p] * rn);
                *(bf16x8*)(xn + (size_t)(p0 + p) * CDIM + cq * 64 + j * 8) = pk;
            }
        }
    } else {
        // ---- feat branch: 64 rows per block ----
        float* tile = (float*)sm;               // [64][257]
        int r0 = (b - 36) * 64;
        #pragma unroll
        for (int i = 0; i < 64; ++i) {
            int idx = t + i * 256;
            int r = idx >> 8, c = idx & 255;
            tile[r * 257 + c] = feat[(size_t)(r0 + r) * CDIM + c];
        }
        __syncthreads();
        int row = t >> 2, q = t & 3;
        float s = 0.f;
        #pragma unroll
        for (int i = 0; i < 64; ++i) {
            float v = tile[row * 257 + q * 64 + i];
            s = fmaf(v, v, s);
        }
        s += __shfl_xor(s, 1, 64);
        s += __shfl_xor(s, 2, 64);
        float rn = 1.0f / fmaxf(sqrtf(s), 1e-12f);
        // fnorm row-major bf16 (normalized — used for cosine score only)
        #pragma unroll
        for (int j = 0; j < 8; ++j) {
            bf16x8 pk;
            #pragma unroll
            for (int jj = 0; jj < 8; ++jj)
                pk[jj] = (short)f2bf(tile[row * 257 + q * 64 + j * 8 + jj] * rn);
            *(bf16x8*)(fnorm + (size_t)(r0 + row) * CDIM + q * 64 + j * 8) = pk;
        }
        __syncthreads();
        // F2T transposed chunk: RAW feat (reference gathers un-normalized feat_units)
        {
            int rp = (t & 31) * 2, cg = t >> 5;
            #pragma unroll
            for (int i = 0; i < 32; ++i) {
                int c = i * 8 + cg;
                unsigned u0 = f2bf(tile[rp * 257 + c]);
                unsigned u1 = f2bf(tile[(rp + 1) * 257 + c]);
                *(unsigned*)(F2T + (size_t)c * KDIM + r0 + rp) = u0 | (u1 << 16);
            }
        }
        // label rows 256..259 (raw)
        {
            int ch = t >> 6, r = t & 63;
            F2T[(size_t)(256 + ch) * KDIM + r0 + r] = f2bf(label[(size_t)(r0 + r) * 4 + ch]);
        }
        // zero rows 260..319
        #pragma unroll
        for (int i = 0; i < 15; ++i) {
            int idx = t + i * 256;
            int zr = idx >> 6, zc = idx & 63;
            F2T[(size_t)(260 + zr) * KDIM + r0 + zc] = 0;
        }
    }
}

// ================= Kernel 2: bf16 MFMA GEMM1  score = xn(2304x256) @ fnorm(2048x256)^T =================
__global__ __launch_bounds__(256) void k_gemm1(const unsigned short* __restrict__ A,
                                               const unsigned short* __restrict__ B,
                                               float* __restrict__ C) {
    __shared__ __align__(16) unsigned short smA[2][128 * 32];
    __shared__ __align__(16) unsigned short smB[2][128 * 32];
    int t = threadIdx.x, l = t & 63, w = t >> 6;
    int m0 = blockIdx.y * 128, n0 = blockIdx.x * 128;
    int wr = w >> 1, wc = w & 1;

    f32x4 acc[4][4] = {};

    #pragma unroll
    for (int r = 0; r < 2; ++r) {
        int row = r * 64 + w * 16 + (l >> 2);
        int ch  = (l & 3) ^ ((row >> 1) & 3);
        gload16(A + (size_t)(m0 + row) * CDIM + ch * 8, &smA[0][(r * 64 + w * 16) * 32]);
        gload16(B + (size_t)(n0 + row) * CDIM + ch * 8, &smB[0][(r * 64 + w * 16) * 32]);
    }
    __syncthreads();

    for (int ks = 0; ks < 8; ++ks) {
        int cur = ks & 1;
        if (ks < 7) {
            int k0 = (ks + 1) * 32;
            #pragma unroll
            for (int r = 0; r < 2; ++r) {
                int row = r * 64 + w * 16 + (l >> 2);
                int ch  = (l & 3) ^ ((row >> 1) & 3);
                gload16(A + (size_t)(m0 + row) * CDIM + k0 + ch * 8, &smA[cur ^ 1][(r * 64 + w * 16) * 32]);
                gload16(B + (size_t)(n0 + row) * CDIM + k0 + ch * 8, &smB[cur ^ 1][(r * 64 + w * 16) * 32]);
            }
        }
        bf16x8 av[4], bv[4];
        #pragma unroll
        for (int mi = 0; mi < 4; ++mi) {
            int R = wr * 64 + mi * 16 + (l & 15);
            av[mi] = *(const bf16x8*)&smA[cur][R * 32 + (((l >> 4) ^ ((R >> 1) & 3)) << 3)];
        }
        #pragma unroll
        for (int ni = 0; ni < 4; ++ni) {
            int R = wc * 64 + ni * 16 + (l & 15);
            bv[ni] = *(const bf16x8*)&smB[cur][R * 32 + (((l >> 4) ^ ((R >> 1) & 3)) << 3)];
        }
        #pragma unroll
        for (int mi = 0; mi < 4; ++mi)
            #pragma unroll
            for (int ni = 0; ni < 4; ++ni)
                acc[mi][ni] = __builtin_amdgcn_mfma_f32_16x16x32_bf16(av[mi], bv[ni], acc[mi][ni], 0, 0, 0);
        __syncthreads();
    }

    #pragma unroll
    for (int mi = 0; mi < 4; ++mi)
        #pragma unroll
        for (int ni = 0; ni < 4; ++ni) {
            int rbase = m0 + wr * 64 + mi * 16 + (l >> 4) * 4;
            int cidx  = n0 + wc * 64 + ni * 16 + (l & 15);
            #pragma unroll
            for (int r = 0; r < 4; ++r)
                C[(size_t)(rbase + r) * KDIM + cidx] = acc[mi][ni][r];
        }
}

// ================= Kernel 3: wave-per-row softmax + bisection top-204 -> Wm bf16 =================
// 576 blocks x 4 waves; zero barriers, zero LDS. Lane l holds cols {j*256 + l*4 .. +3}.
__global__ __launch_bounds__(256) void k_select(const float* __restrict__ score,
                                                unsigned short* __restrict__ Wm) {
    int t = threadIdx.x, l = t & 63, w = t >> 6;
    int row = blockIdx.x * 4 + w;
    const float* srow = score + (size_t)row * KDIM;

    float s[32];
    #pragma unroll
    for (int j = 0; j < 8; ++j) {
        float4 v = *(const float4*)(srow + j * 256 + l * 4);
        s[j * 4 + 0] = v.x; s[j * 4 + 1] = v.y; s[j * 4 + 2] = v.z; s[j * 4 + 3] = v.w;
    }

    // softmax denom (|score|<=~1: no max-shift needed)
    float d = 0.f;
    #pragma unroll
    for (int j = 0; j < 32; ++j) d += __expf(s[j]);
    #pragma unroll
    for (int off = 32; off; off >>= 1) d += __shfl_xor(d, off, 64);
    float rd = 1.0f / d;

    // 22-iter bisection on score domain: lo s.t. count(> lo) >= 204
    float lo = -1.5f, hi = 1.5f;
    #pragma unroll 1
    for (int it = 0; it < 22; ++it) {
        float mid = 0.5f * (lo + hi);
        int c = 0;
        #pragma unroll
        for (int j = 0; j < 32; ++j) c += (s[j] > mid) ? 1 : 0;
        #pragma unroll
        for (int off = 32; off; off >>= 1) c += __shfl_xor(c, off, 64);
        if (c >= TOPK) lo = mid; else hi = mid;
    }

    // masked softmax weights, bf16
    #pragma unroll
    for (int j = 0; j < 8; ++j) {
        ushort4 pk;
        pk.x = (s[j*4+0] > lo) ? f2bf(__expf(s[j*4+0]) * rd) : (unsigned short)0;
        pk.y = (s[j*4+1] > lo) ? f2bf(__expf(s[j*4+1]) * rd) : (unsigned short)0;
        pk.z = (s[j*4+2] > lo) ? f2bf(__expf(s[j*4+2]) * rd) : (unsigned short)0;
        pk.w = (s[j*4+3] > lo) ? f2bf(__expf(s[j*4+3]) * rd) : (unsigned short)0;
        *(ushort4*)(Wm + (size_t)row * KDIM + j * 256 + l * 4) = pk;
    }
}

// ================= Kernel 4: GEMM2  out_xy^T = W(2304x2048) @ F2T(320x2048)^T =================
__global__ __launch_bounds__(256) void k_gemm2(const unsigned short* __restrict__ W,
                                               const unsigned short* __restrict__ F2T,
                                               float* __restrict__ out) {
    __shared__ __align__(16) char sm[65536];
    int t = threadIdx.x, l = t & 63, w = t >> 6;
    int m0 = blockIdx.y * 64, n0 = blockIdx.x * 64;
    char* wbase = sm + w * 16384;
    int   kb    = w * 512;

    f32x4 acc[4][4] = {};

    #pragma unroll
    for (int i = 0; i < 4; ++i) {
        int row = i * 16 + (l >> 2);
        int ch  = (l & 3) ^ ((row >> 1) & 3);
        gload16(W   + (size_t)(m0 + row) * KDIM + kb + ch * 8, wbase + i * 1024);
        gload16(F2T + (size_t)(n0 + row) * KDIM + kb + ch * 8, wbase + 8192 + i * 1024);
    }

    for (int ks = 0; ks < 16; ++ks) {
        int cur = ks & 1;
        if (ks < 15) {
            int koff = kb + (ks + 1) * 32;
            #pragma unroll
            for (int i = 0; i < 4; ++i) {
                int row = i * 16 + (l >> 2);
                int ch  = (l & 3) ^ ((row >> 1) & 3);
                gload16(W   + (size_t)(m0 + row) * KDIM + koff + ch * 8, wbase + (cur ^ 1) * 4096 + i * 1024);
                gload16(F2T + (size_t)(n0 + row) * KDIM + koff + ch * 8, wbase + 8192 + (cur ^ 1) * 4096 + i * 1024);
            }
            asm volatile("s_waitcnt vmcnt(8)" ::: "memory");
        } else {
            asm volatile("s_waitcnt vmcnt(0)" ::: "memory");
        }
        bf16x8 av[4], bv[4];
        #pragma unroll
        for (int mi = 0; mi < 4; ++mi) {
            int R = mi * 16 + (l & 15);
            av[mi] = *(const bf16x8*)(wbase + cur * 4096 + R * 64 + (((l >> 4) ^ ((R >> 1) & 3)) << 4));
        }
        #pragma unroll
        for (int ni = 0; ni < 4; ++ni) {
            int R = ni * 16 + (l & 15);
            bv[ni] = *(const bf16x8*)(wbase + 8192 + cur * 4096 + R * 64 + (((l >> 4) ^ ((R >> 1) & 3)) << 4));
        }
        #pragma unroll
        for (int mi = 0; mi < 4; ++mi)
            #pragma unroll
            for (int ni = 0; ni < 4; ++ni)
                acc[mi][ni] = __builtin_amdgcn_mfma_f32_16x16x32_bf16(av[mi], bv[ni], acc[mi][ni], 0, 0, 0);
    }

    __syncthreads();
    float* tl = (float*)sm;                 // [2][64][65] f32
    if (w >= 2) {
        float* dst = tl + (w - 2) * 64 * 65;
        #pragma unroll
        for (int mi = 0; mi < 4; ++mi)
            #pragma unroll
            for (int ni = 0; ni < 4; ++ni) {
                int rr = mi * 16 + (l >> 4) * 4;
                int cc = ni * 16 + (l & 15);
                #pragma unroll
                for (int r = 0; r < 4; ++r)
                    dst[(rr + r) * 65 + cc] = acc[mi][ni][r];
            }
    }
    __syncthreads();
    if (w < 2) {
        float* dst = tl + w * 64 * 65;
        #pragma unroll
        for (int mi = 0; mi < 4; ++mi)
            #pragma unroll
            for (int ni = 0; ni < 4; ++ni) {
                int rr = mi * 16 + (l >> 4) * 4;
                int cc = ni * 16 + (l & 15);
                #pragma unroll
                for (int r = 0; r < 4; ++r)
                    dst[(rr + r) * 65 + cc] += acc[mi][ni][r];
            }
    }
    __syncthreads();
    int pl = t & 63, cg = t >> 6;
    #pragma unroll
    for (int i = 0; i < 16; ++i) {
        int cc = cg * 16 + i;
        int c_out = n0 + cc;
        int orow;
        if (c_out < 256) orow = 256 + c_out;
        else if (c_out < 260) orow = 512 + (c_out - 256);
        else continue;
        out[(size_t)orow * N_PIX + m0 + pl] = tl[pl * 65 + cc] + tl[64 * 65 + pl * 65 + cc];
    }
}

extern "C" void kernel_launch(void* const* d_in, const int* in_sizes, int n_in,
                              void* d_out, int out_size, void* d_ws, size_t ws_size,
                              hipStream_t stream) {
    const float* x     = (const float*)d_in[0];   // (1,256,48,48)
    const float* feat  = (const float*)d_in[1];   // (2048,256)
    const float* label = (const float*)d_in[2];   // (2048,4)
    float* out   = (float*)d_out;                 // (1,516,48,48) then score
    float* score = out + 516 * N_PIX;             // (2304,2048)

    char* ws = (char*)d_ws;
    unsigned short* xn    = (unsigned short*)(ws);             // 2304*256*2 = 1179648
    unsigned short* fnorm = (unsigned short*)(ws + 1179648);   // 2048*256*2 = 1048576
    unsigned short* F2T   = (unsigned short*)(ws + 2228224);   // 320*2048*2 = 1310720
    unsigned short* Wm    = (unsigned short*)(ws + 3538944);   // 2304*2048*2 = 9437184

    k_prep  <<<68,           256, 0, stream>>>(x, feat, label, out, xn, fnorm, F2T);
    k_gemm1 <<<dim3(16, 18), 256, 0, stream>>>(xn, fnorm, score);
    k_select<<<576,          256, 0, stream>>>(score, Wm);
    k_gemm2 <<<dim3(5, 36),  256, 0, stream>>>(Wm, F2T, out);
}